// Round 6
// baseline (1234.979 us; speedup 1.0000x reference)
//
#include <hip/hip_runtime.h>
#include <hip/hip_bf16.h>

// Problem constants (from reference)
constexpr int N_NODES = 50000;
constexpr int N_EDGES = 600000;
constexpr int ND = 128;   // NODE_DIM
constexpr int ED = 64;    // EDGE_DIM
constexpr int MD = 128;   // MSG_DIM
constexpr int H1 = 32;    // edge MLP hidden
constexpr int H2 = 64;    // node MLP hidden

typedef __attribute__((ext_vector_type(8))) short short8;   // 8 bf16 (4 VGPRs)
typedef __attribute__((ext_vector_type(4))) float f32x4;    // MFMA acc
typedef __attribute__((ext_vector_type(4))) unsigned int uint32x4;

#define MFMA16(a, b, c) __builtin_amdgcn_mfma_f32_16x16x32_bf16((a), (b), (c), 0, 0, 0)

// ---------------- workspace layout (bytes) ----------------
// (msgs/pos/counts/offsets regions retained as dead space for layout stability)
constexpr int COUNTS_PAD = 53248;
constexpr size_t WS_MSGS    = 0;                                        // (unused now)
constexpr size_t WS_PRE     = WS_MSGS + (size_t)N_EDGES * MD * 2;       // N*128 bf16 (a1|a2|a3)
constexpr size_t WS_POS     = WS_PRE + (size_t)N_NODES * 128 * 2;       // (unused)
constexpr size_t WS_COUNTS  = WS_POS + (size_t)N_EDGES * 4;             // (unused)
constexpr size_t WS_OFFSETS = WS_COUNTS + (size_t)COUNTS_PAD * 4;       // (unused)
constexpr size_t WS_WFE     = ((WS_OFFSETS + (size_t)(N_NODES + 1) * 4 + 15) / 16) * 16;
constexpr size_t WS_WFN     = WS_WFE + (size_t)44 * 64 * 16;            // 44 edge frags
constexpr size_t WS_END     = WS_WFN + (size_t)32 * 64 * 16;            // 32 node frags

__device__ inline float bflo(unsigned u) { return __uint_as_float(u << 16); }
__device__ inline float bfhi(unsigned u) { return __uint_as_float(u & 0xffff0000u); }
__device__ inline short f2bf(float f) {
    __hip_bfloat16 h = __float2bfloat16(f);
    return *reinterpret_cast<short*>(&h);
}
// packed f32 pair -> bf16 pair (1 instr)
__device__ inline unsigned pkbf(float a, float b) {
    unsigned r;
    asm("v_cvt_pk_bf16_f32 %0, %1, %2" : "=v"(r) : "v"(a), "v"(b));
    return r;
}
__device__ inline unsigned prelu(float a, float b) {
    return pkbf(fmaxf(a, 0.0f), fmaxf(b, 0.0f));
}
__device__ inline short8 pack8(unsigned w0, unsigned w1, unsigned w2, unsigned w3) {
    uint32x4 t{w0, w1, w2, w3};
    return __builtin_bit_cast(short8, t);
}

// Hidden-dim relabeling for swapped-operand layer chaining:
// layer i's output at lane(q,m16) reg (mt,r) carries h = mt*16 + q*4 + r,
// which slots into next layer's B-operand k = kt*32 + q*8 + j with
// mt = kt*2 + (j>>2), r = j&3. Fold h(k) into the weight row order here.
__device__ inline int hperm(int kt, int kq) {   // kq = quad*8+j in [0,32)
    return (kt * 2 + ((kq >> 2) & 1)) * 16 + ((kq >> 3) & 3) * 4 + (kq & 3);
}

// ---------------- weight fragment prep (once, tiny) ----------------
// All wfE frags are A-operands (lane holds W[k=quad*8+j][m=lane&15] = A[m][k]
// of W^T). Frag ids: We1e=0..3 (kt*2+mt), We2=4..11 (mt), Wn1b=12..27
// (kt*4+mt), Wn2=28..43 (kt*8+mt). We2/Wn1b/Wn2 rows permuted by hperm.
// wfN frag ids: combined 128x128 B = [We1[0:128] | We1[128:256] | Wn1[0:128]] -> kt*8+nt.
__global__ __launch_bounds__(256) void wprep(
    const float* __restrict__ We1, const float* __restrict__ We2,
    const float* __restrict__ Wn1, const float* __restrict__ Wn2,
    short8* __restrict__ wfE, short8* __restrict__ wfN)
{
    const int g = blockIdx.x * 256 + threadIdx.x;   // 0..4863
    const int lane = g & 63;
    const int f = g >> 6;                            // 0..75
    const int m16 = lane & 15, quad = lane >> 4;
    short v[8];
    if (f < 44) {
        #pragma unroll
        for (int j = 0; j < 8; ++j) {
            const int kq = quad * 8 + j;
            float s;
            if (f < 4) {
                const int kt = f >> 1, mt = f & 1;
                s = We1[(size_t)(2 * ND + kt * 32 + kq) * H1 + mt * 16 + m16];
            } else if (f < 12) {
                const int mt = f - 4;
                s = We2[(size_t)hperm(0, kq) * MD + mt * 16 + m16];
            } else if (f < 28) {
                const int ff = f - 12, kt = ff >> 2, mt = ff & 3;
                s = Wn1[(size_t)(ND + hperm(kt, kq)) * H2 + mt * 16 + m16];
            } else {
                const int ff = f - 28, kt = ff >> 3, mt = ff & 7;
                s = Wn2[(size_t)hperm(kt, kq) * MD + mt * 16 + m16];
            }
            v[j] = f2bf(s);
        }
        wfE[g] = short8{v[0], v[1], v[2], v[3], v[4], v[5], v[6], v[7]};
    } else {
        const int ff = f - 44, kt = ff >> 3, nt = ff & 7;
        const int n = nt * 16 + m16;
        #pragma unroll
        for (int j = 0; j < 8; ++j) {
            const int k = kt * 32 + quad * 8 + j;
            float s;
            if (n < 32)      s = We1[(size_t)k * H1 + n];
            else if (n < 64) s = We1[(size_t)(ND + k) * H1 + (n - 32)];
            else             s = Wn1[(size_t)k * H2 + (n - 64)];
            v[j] = f2bf(s);
        }
        wfN[(size_t)(f - 44) * 64 + lane] = short8{v[0], v[1], v[2], v[3], v[4], v[5], v[6], v[7]};
    }
}

// ------- node precompute (pre = nf @ B128x128) + out init (out = nf) -------
__global__ __launch_bounds__(256) void node_pre_mfma(
    const float* __restrict__ nf, const short8* __restrict__ wfN,
    unsigned short* __restrict__ pre, float* __restrict__ out)
{
    __shared__ short ost[4][2048];   // per-wave 16x128 out stage
    const int tid = threadIdx.x;
    const int w = tid >> 6, lane = tid & 63;
    const int m16 = lane & 15, quad = lane >> 4;
    const int n0 = blockIdx.x * 64 + w * 16;

    // ---- out = nf (coalesced block copy of 64 node rows) ----
    {
        const int nbase = blockIdx.x * 64;
        const int nrem = min(64, N_NODES - nbase);
        const float4* s4 = (const float4*)(nf + (size_t)nbase * ND);
        float4* d4 = (float4*)(out + (size_t)nbase * ND);
        const int tot = nrem * (ND / 4);
        for (int i = tid; i < tot; i += 256) d4[i] = s4[i];
    }

    short8 a[4];
    #pragma unroll
    for (int kt = 0; kt < 4; ++kt) {
        const int node = min(n0 + m16, N_NODES - 1);
        const float* pn = nf + (size_t)node * ND + kt * 32 + quad * 8;
        const float4 f0 = *(const float4*)pn;
        const float4 f1 = *(const float4*)(pn + 4);
        a[kt] = pack8(pkbf(f0.x, f0.y), pkbf(f0.z, f0.w),
                      pkbf(f1.x, f1.y), pkbf(f1.z, f1.w));
    }
    f32x4 acc[8];
    #pragma unroll
    for (int nt = 0; nt < 8; ++nt) acc[nt] = f32x4{0.f, 0.f, 0.f, 0.f};
    #pragma unroll
    for (int kt = 0; kt < 4; ++kt) {
        #pragma unroll
        for (int nt = 0; nt < 8; ++nt)
            acc[nt] = MFMA16(a[kt], wfN[(size_t)(kt * 8 + nt) * 64 + lane], acc[nt]);
    }
    short* o = &ost[w][0];
    #pragma unroll
    for (int nt = 0; nt < 8; ++nt)
        #pragma unroll
        for (int r = 0; r < 4; ++r)
            o[(quad * 4 + r) * 128 + nt * 16 + m16] = f2bf(acc[nt][r]);  // no relu
    asm volatile("s_waitcnt lgkmcnt(0)" ::: "memory");
    #pragma unroll
    for (int i = 0; i < 4; ++i) {
        const int row = i * 4 + quad;
        const int node = n0 + row;
        if (node < N_NODES) {
            const uint4 v = ((const uint4*)(o + row * 128))[m16];
            *((uint4*)(pre + (size_t)node * 128) + m16) = v;
        }
    }
}

// ---------------- fused 4-layer edge MLP, swapped-operand, 2 tiles/wave -----
// R3-verified structure: 128 edges/block, 4 independent waves x 2 tiles x 16
// edges; coalesced 4-lanes-per-edge gather with LDS transpose; each wfE
// fragment loaded once feeds two MFMA chains (2x ILP). Output: per-lane f32
// atomicAdd scatter directly into out[dst] - no msgs buffer, no CSR, no
// gather pass (saves 307MB HBM round-trip; out is L2/L3-resident).
__global__ __launch_bounds__(256, 4) void edge_mfma(
    const float* __restrict__ ef, const int* __restrict__ eidx,
    const unsigned short* __restrict__ pre,
    const short8* __restrict__ wfE,
    const float* __restrict__ be1, const float* __restrict__ be2,
    const float* __restrict__ bn1, const float* __restrict__ bn2,
    float* __restrict__ out)
{
    constexpr int TE = 128;
    __shared__ __align__(16) char sws[4][9216];

    const int tid = threadIdx.x;
    const int e0 = blockIdx.x * TE;
    const bool hasB = (e0 + 64) < N_EDGES;          // block-uniform (last block only A)
    const int w = tid >> 6, lane = tid & 63;
    const int m16 = lane & 15, q = lane >> 4;
    const int er0 = w * 16;
    char* swsb = &sws[w][0];

    // ---- front-load ef global loads for both tiles ----
    float4 efv[2][4];
    {
        const float* pe = ef + (size_t)(e0 + er0 + m16) * ED + q * 8;
        efv[0][0] = *(const float4*)pe;
        efv[0][1] = *(const float4*)(pe + 4);
        efv[0][2] = *(const float4*)(pe + 32);
        efv[0][3] = *(const float4*)(pe + 36);
        if (hasB) {
            const float* pe2 = pe + (size_t)64 * ED;
            efv[1][0] = *(const float4*)pe2;
            efv[1][1] = *(const float4*)(pe2 + 4);
            efv[1][2] = *(const float4*)(pe2 + 32);
            efv[1][3] = *(const float4*)(pe2 + 36);
        }
    }

    // ---- gather: 4 lanes/edge, both passes' loads issued before LDS writes ----
    {
        const int et = tid >> 2, p4 = tid & 3;      // et in [16w,16w+16)
        const int eA = e0 + et;
        const int srcA = eidx[eA];
        const int dstA = eidx[N_EDGES + eA];
        const uint4* paA = (const uint4*)(pre + (size_t)srcA * 128);
        const uint4* pdA = (const uint4*)(pre + (size_t)dstA * 128);
        const uint4 uaA = paA[p4];
        const uint4 udA = pdA[4 + p4];
        const uint4 s0A = pdA[8 + 2 * p4];
        const uint4 s1A = pdA[9 + 2 * p4];

        uint4 uaB, udB, s0B, s1B;
        if (hasB) {
            const int eB = eA + 64;
            const int srcB = eidx[eB];
            const int dstB = eidx[N_EDGES + eB];
            const uint4* paB = (const uint4*)(pre + (size_t)srcB * 128);
            const uint4* pdB = (const uint4*)(pre + (size_t)dstB * 128);
            uaB = paB[p4];
            udB = pdB[4 + p4];
            s0B = pdB[8 + 2 * p4];
            s1B = pdB[9 + 2 * p4];
        }
        const float4 b0 = ((const float4*)be1)[2 * p4];
        const float4 b1 = ((const float4*)be1)[2 * p4 + 1];

        char* wbase = &sws[et >> 4][0] + (et & 15) * 144;
        {
            float4 r0, r1;
            r0.x = bflo(uaA.x) + bflo(udA.x) + b0.x;
            r0.y = bfhi(uaA.x) + bfhi(udA.x) + b0.y;
            r0.z = bflo(uaA.y) + bflo(udA.y) + b0.z;
            r0.w = bfhi(uaA.y) + bfhi(udA.y) + b0.w;
            r1.x = bflo(uaA.z) + bflo(udA.z) + b1.x;
            r1.y = bfhi(uaA.z) + bfhi(udA.z) + b1.y;
            r1.z = bflo(uaA.w) + bflo(udA.w) + b1.z;
            r1.w = bfhi(uaA.w) + bfhi(udA.w) + b1.w;
            *(float4*)(wbase + p4 * 32) = r0;
            *(float4*)(wbase + p4 * 32 + 16) = r1;
            *(uint4*)(wbase + 2304 + p4 * 32) = s0A;
            *(uint4*)(wbase + 2304 + p4 * 32 + 16) = s1A;
        }
        if (hasB) {
            float4 r0, r1;
            r0.x = bflo(uaB.x) + bflo(udB.x) + b0.x;
            r0.y = bfhi(uaB.x) + bfhi(udB.x) + b0.y;
            r0.z = bflo(uaB.y) + bflo(udB.y) + b0.z;
            r0.w = bfhi(uaB.y) + bfhi(udB.y) + b0.w;
            r1.x = bflo(uaB.z) + bflo(udB.z) + b1.x;
            r1.y = bfhi(uaB.z) + bfhi(udB.z) + b1.y;
            r1.z = bflo(uaB.w) + bflo(udB.w) + b1.z;
            r1.w = bfhi(uaB.w) + bfhi(udB.w) + b1.w;
            *(float4*)(wbase + 4608 + p4 * 32) = r0;
            *(float4*)(wbase + 4608 + p4 * 32 + 16) = r1;
            *(uint4*)(wbase + 4608 + 2304 + p4 * 32) = s0B;
            *(uint4*)(wbase + 4608 + 2304 + p4 * 32 + 16) = s1B;
        }
    }
    // wave-local LDS handoff (all writes by this wave's lanes)
    asm volatile("s_waitcnt lgkmcnt(0)" ::: "memory");

    short8 aef[2][2];
    #pragma unroll
    for (int t = 0; t < 2; ++t) {
        aef[t][0] = pack8(pkbf(efv[t][0].x, efv[t][0].y), pkbf(efv[t][0].z, efv[t][0].w),
                          pkbf(efv[t][1].x, efv[t][1].y), pkbf(efv[t][1].z, efv[t][1].w));
        aef[t][1] = pack8(pkbf(efv[t][2].x, efv[t][2].y), pkbf(efv[t][2].z, efv[t][2].w),
                          pkbf(efv[t][3].x, efv[t][3].y), pkbf(efv[t][3].z, efv[t][3].w));
    }

    // ---- L1: C[h1][edge] = l1init + We1e^T x ef (both tiles share frags) ----
    f32x4 acc1[2][2];
    #pragma unroll
    for (int t = 0; t < 2; ++t)
        #pragma unroll
        for (int mt = 0; mt < 2; ++mt)
            acc1[t][mt] = *(const f32x4*)(swsb + t * 4608 + m16 * 144 + mt * 64 + q * 16);
    #pragma unroll
    for (int kt = 0; kt < 2; ++kt)
        #pragma unroll
        for (int mt = 0; mt < 2; ++mt) {
            const short8 wf = wfE[(size_t)(kt * 2 + mt) * 64 + lane];
            acc1[0][mt] = MFMA16(wf, aef[0][kt], acc1[0][mt]);
            acc1[1][mt] = MFMA16(wf, aef[1][kt], acc1[1][mt]);
        }

    short8 b2[2];
    #pragma unroll
    for (int t = 0; t < 2; ++t)
        b2[t] = pack8(prelu(acc1[t][0][0], acc1[t][0][1]), prelu(acc1[t][0][2], acc1[t][0][3]),
                      prelu(acc1[t][1][0], acc1[t][1][1]), prelu(acc1[t][1][2], acc1[t][1][3]));

    // ---- L2: msg(128) = relu(We2^T x h + be2) ----
    f32x4 acc2[2][8];
    #pragma unroll
    for (int mt = 0; mt < 8; ++mt) {
        const float4 bb = *(const float4*)(be2 + mt * 16 + q * 4);
        const short8 wf = wfE[(size_t)(4 + mt) * 64 + lane];
        acc2[0][mt] = f32x4{bb.x, bb.y, bb.z, bb.w};
        acc2[1][mt] = acc2[0][mt];
        acc2[0][mt] = MFMA16(wf, b2[0], acc2[0][mt]);
        acc2[1][mt] = MFMA16(wf, b2[1], acc2[1][mt]);
    }
    short8 b3[2][4];
    #pragma unroll
    for (int t = 0; t < 2; ++t)
        #pragma unroll
        for (int kt = 0; kt < 4; ++kt)
            b3[t][kt] = pack8(prelu(acc2[t][2 * kt][0], acc2[t][2 * kt][1]),
                              prelu(acc2[t][2 * kt][2], acc2[t][2 * kt][3]),
                              prelu(acc2[t][2 * kt + 1][0], acc2[t][2 * kt + 1][1]),
                              prelu(acc2[t][2 * kt + 1][2], acc2[t][2 * kt + 1][3]));

    // ---- L3: h2(64) = relu(a3 + bn1 + Wn1b^T x msg) ----
    f32x4 acc3[2][4];
    #pragma unroll
    for (int mt = 0; mt < 4; ++mt) {
        const float4 bb = *(const float4*)(bn1 + mt * 16 + q * 4);
        #pragma unroll
        for (int t = 0; t < 2; ++t) {
            const uint2 ua = *(const uint2*)(swsb + t * 4608 + 2304 + m16 * 144 + mt * 32 + q * 8);
            acc3[t][mt] = f32x4{bb.x + bflo(ua.x), bb.y + bfhi(ua.x),
                                bb.z + bflo(ua.y), bb.w + bfhi(ua.y)};
        }
    }
    #pragma unroll
    for (int kt = 0; kt < 4; ++kt)
        #pragma unroll
        for (int mt = 0; mt < 4; ++mt) {
            const short8 wf = wfE[(size_t)(12 + kt * 4 + mt) * 64 + lane];
            acc3[0][mt] = MFMA16(wf, b3[0][kt], acc3[0][mt]);
            acc3[1][mt] = MFMA16(wf, b3[1][kt], acc3[1][mt]);
        }
    short8 b4[2][2];
    #pragma unroll
    for (int t = 0; t < 2; ++t)
        #pragma unroll
        for (int kt = 0; kt < 2; ++kt)
            b4[t][kt] = pack8(prelu(acc3[t][2 * kt][0], acc3[t][2 * kt][1]),
                              prelu(acc3[t][2 * kt][2], acc3[t][2 * kt][3]),
                              prelu(acc3[t][2 * kt + 1][0], acc3[t][2 * kt + 1][1]),
                              prelu(acc3[t][2 * kt + 1][2], acc3[t][2 * kt + 1][3]));

    // ---- L4: out(128) = relu(Wn2^T x h2 + bn2) ----
    f32x4 acc4[2][8];
    #pragma unroll
    for (int mt = 0; mt < 8; ++mt) {
        const float4 bb = *(const float4*)(bn2 + mt * 16 + q * 4);
        acc4[0][mt] = f32x4{bb.x, bb.y, bb.z, bb.w};
        acc4[1][mt] = acc4[0][mt];
    }
    #pragma unroll
    for (int kt = 0; kt < 2; ++kt)
        #pragma unroll
        for (int mt = 0; mt < 8; ++mt) {
            const short8 wf = wfE[(size_t)(28 + kt * 8 + mt) * 64 + lane];
            acc4[0][mt] = MFMA16(wf, b4[0][kt], acc4[0][mt]);
            acc4[1][mt] = MFMA16(wf, b4[1][kt], acc4[1][mt]);
        }

    // ---- per-lane atomic scatter-add into out[dst] (L2/L3-resident) ----
    // lane (q,m16) owns h = mt*16 + q*4 + r of edge col m16 (tile t).
    #pragma unroll
    for (int t = 0; t < 2; ++t) {
        if (t == 0 || hasB) {
            const int dstv = eidx[N_EDGES + e0 + t * 64 + er0 + m16];
            float* po = out + (size_t)dstv * ND + q * 4;
            #pragma unroll
            for (int mt = 0; mt < 8; ++mt) {
                #pragma unroll
                for (int r = 0; r < 4; ++r)
                    atomicAdd(po + mt * 16 + r, fmaxf(acc4[t][mt][r], 0.0f));
            }
        }
    }
}

extern "C" void kernel_launch(void* const* d_in, const int* in_sizes, int n_in,
                              void* d_out, int out_size, void* d_ws, size_t ws_size,
                              hipStream_t stream) {
    const float* nf  = (const float*)d_in[0];
    const float* ef  = (const float*)d_in[1];
    const int*  eidx = (const int*)d_in[2];
    const float* We1 = (const float*)d_in[3];
    const float* be1 = (const float*)d_in[4];
    const float* We2 = (const float*)d_in[5];
    const float* be2 = (const float*)d_in[6];
    const float* Wn1 = (const float*)d_in[7];
    const float* bn1 = (const float*)d_in[8];
    const float* Wn2 = (const float*)d_in[9];
    const float* bn2 = (const float*)d_in[10];
    float* out = (float*)d_out;

    char* ws = (char*)d_ws;
    unsigned short* pre  = (unsigned short*)(ws + WS_PRE);
    short8* wfE          = (short8*)(ws + WS_WFE);
    short8* wfN          = (short8*)(ws + WS_WFN);
    (void)ws_size; (void)WS_END;

    wprep<<<19, 256, 0, stream>>>(We1, We2, Wn1, Wn2, wfE, wfN);
    node_pre_mfma<<<(N_NODES + 63) / 64, 256, 0, stream>>>(nf, wfN, pre, out);
    edge_mfma<<<(N_EDGES + 127) / 128, 256, 0, stream>>>(
        ef, eidx, pre, wfE, be1, be2, bn1, bn2, out);
}

// Round 8
// 408.440 us; speedup vs baseline: 3.0236x; 3.0236x over previous
//
#include <hip/hip_runtime.h>
#include <hip/hip_bf16.h>

// Problem constants (from reference)
constexpr int N_NODES = 50000;
constexpr int N_EDGES = 600000;
constexpr int ND = 128;   // NODE_DIM
constexpr int ED = 64;    // EDGE_DIM
constexpr int MD = 128;   // MSG_DIM
constexpr int H1 = 32;    // edge MLP hidden
constexpr int H2 = 64;    // node MLP hidden

typedef __attribute__((ext_vector_type(8))) short short8;   // 8 bf16 (4 VGPRs)
typedef __attribute__((ext_vector_type(4))) float f32x4;    // MFMA acc
typedef __attribute__((ext_vector_type(4))) unsigned int uint32x4;

#define MFMA16(a, b, c) __builtin_amdgcn_mfma_f32_16x16x32_bf16((a), (b), (c), 0, 0, 0)

// ---------------- workspace layout (bytes) ----------------
constexpr int COUNTS_PAD = 53248;   // 1024*52 (scan CHUNK=52, int4 loads)
constexpr size_t WS_SLOTREC = 0;                                        // E uint4 (slot->{e,src,dst})
constexpr size_t WS_PRE     = WS_SLOTREC + (size_t)N_EDGES * 16;        // N*128 bf16 (a1|a2|a3)
constexpr size_t WS_POS     = WS_PRE + (size_t)N_NODES * 128 * 2;       // E int
constexpr size_t WS_COUNTS  = WS_POS + (size_t)N_EDGES * 4;             // COUNTS_PAD int
constexpr size_t WS_OFFSETS = WS_COUNTS + (size_t)COUNTS_PAD * 4;       // N+1 int
constexpr size_t WS_WFE     = ((WS_OFFSETS + (size_t)(N_NODES + 1) * 4 + 15) / 16) * 16;
constexpr size_t WS_WFN     = WS_WFE + (size_t)44 * 64 * 16;            // 44 edge frags
constexpr size_t WS_END     = WS_WFN + (size_t)32 * 64 * 16;            // 32 node frags

__device__ inline float bflo(unsigned u) { return __uint_as_float(u << 16); }
__device__ inline float bfhi(unsigned u) { return __uint_as_float(u & 0xffff0000u); }
__device__ inline short f2bf(float f) {
    __hip_bfloat16 h = __float2bfloat16(f);
    return *reinterpret_cast<short*>(&h);
}
// packed f32 pair -> bf16 pair (1 instr)
__device__ inline unsigned pkbf(float a, float b) {
    unsigned r;
    asm("v_cvt_pk_bf16_f32 %0, %1, %2" : "=v"(r) : "v"(a), "v"(b));
    return r;
}
__device__ inline unsigned prelu(float a, float b) {
    return pkbf(fmaxf(a, 0.0f), fmaxf(b, 0.0f));
}
__device__ inline short8 pack8(unsigned w0, unsigned w1, unsigned w2, unsigned w3) {
    uint32x4 t{w0, w1, w2, w3};
    return __builtin_bit_cast(short8, t);
}

// Hidden-dim relabeling for swapped-operand layer chaining:
// layer i's output at lane(q,m16) reg (mt,r) carries h = mt*16 + q*4 + r,
// which slots into next layer's B-operand k = kt*32 + q*8 + j with
// mt = kt*2 + (j>>2), r = j&3. Fold h(k) into the weight row order here.
__device__ inline int hperm(int kt, int kq) {   // kq = quad*8+j in [0,32)
    return (kt * 2 + ((kq >> 2) & 1)) * 16 + ((kq >> 3) & 3) * 4 + (kq & 3);
}

// ---------------- weight fragment prep (once, tiny) ----------------
// All wfE frags are A-operands (lane holds W[k=quad*8+j][m=lane&15] = A[m][k]
// of W^T). Frag ids: We1e=0..3 (kt*2+mt), We2=4..11 (mt), Wn1b=12..27
// (kt*4+mt), Wn2=28..43 (kt*8+mt). We2/Wn1b/Wn2 rows permuted by hperm.
// wfN frag ids: combined 128x128 B = [We1[0:128] | We1[128:256] | Wn1[0:128]] -> kt*8+nt.
__global__ __launch_bounds__(256) void wprep(
    const float* __restrict__ We1, const float* __restrict__ We2,
    const float* __restrict__ Wn1, const float* __restrict__ Wn2,
    short8* __restrict__ wfE, short8* __restrict__ wfN)
{
    const int g = blockIdx.x * 256 + threadIdx.x;   // 0..4863
    const int lane = g & 63;
    const int f = g >> 6;                            // 0..75
    const int m16 = lane & 15, quad = lane >> 4;
    short v[8];
    if (f < 44) {
        #pragma unroll
        for (int j = 0; j < 8; ++j) {
            const int kq = quad * 8 + j;
            float s;
            if (f < 4) {
                const int kt = f >> 1, mt = f & 1;
                s = We1[(size_t)(2 * ND + kt * 32 + kq) * H1 + mt * 16 + m16];
            } else if (f < 12) {
                const int mt = f - 4;
                s = We2[(size_t)hperm(0, kq) * MD + mt * 16 + m16];
            } else if (f < 28) {
                const int ff = f - 12, kt = ff >> 2, mt = ff & 3;
                s = Wn1[(size_t)(ND + hperm(kt, kq)) * H2 + mt * 16 + m16];
            } else {
                const int ff = f - 28, kt = ff >> 3, mt = ff & 7;
                s = Wn2[(size_t)hperm(kt, kq) * MD + mt * 16 + m16];
            }
            v[j] = f2bf(s);
        }
        wfE[g] = short8{v[0], v[1], v[2], v[3], v[4], v[5], v[6], v[7]};
    } else {
        const int ff = f - 44, kt = ff >> 3, nt = ff & 7;
        const int n = nt * 16 + m16;
        #pragma unroll
        for (int j = 0; j < 8; ++j) {
            const int k = kt * 32 + quad * 8 + j;
            float s;
            if (n < 32)      s = We1[(size_t)k * H1 + n];
            else if (n < 64) s = We1[(size_t)(ND + k) * H1 + (n - 32)];
            else             s = Wn1[(size_t)k * H2 + (n - 64)];
            v[j] = f2bf(s);
        }
        wfN[(size_t)(f - 44) * 64 + lane] = short8{v[0], v[1], v[2], v[3], v[4], v[5], v[6], v[7]};
    }
}

// ---------------- CSR: histogram + within-segment position -----------------
__global__ __launch_bounds__(256) void hist_pos(const int* __restrict__ eidx,
                                                int* __restrict__ counts,
                                                int* __restrict__ pos) {
    const int e = blockIdx.x * 256 + threadIdx.x;
    if (e < N_EDGES) pos[e] = atomicAdd(&counts[eidx[N_EDGES + e]], 1);
}

__global__ __launch_bounds__(1024) void scan_kernel(const int* __restrict__ counts,
                                                    int* __restrict__ offsets) {
    constexpr int T = 1024;
    const int tid = threadIdx.x;
    const int base = tid * 52;
    int4 v[13];
    int s = 0;
    const int4* pc = (const int4*)(counts + base);
    #pragma unroll
    for (int i = 0; i < 13; ++i) {
        v[i] = pc[i];
        s += v[i].x + v[i].y + v[i].z + v[i].w;
    }
    __shared__ int sm[T];
    sm[tid] = s;
    __syncthreads();
    for (int off = 1; off < T; off <<= 1) {
        const int t = (tid >= off) ? sm[tid - off] : 0;
        __syncthreads();
        sm[tid] += t;
        __syncthreads();
    }
    int run = sm[tid] - s;
    #pragma unroll
    for (int i = 0; i < 13; ++i) {
        const int idx = base + i * 4;
        if (idx     <= N_NODES) offsets[idx]     = run;  run += v[i].x;
        if (idx + 1 <= N_NODES) offsets[idx + 1] = run;  run += v[i].y;
        if (idx + 2 <= N_NODES) offsets[idx + 2] = run;  run += v[i].z;
        if (idx + 3 <= N_NODES) offsets[idx + 3] = run;  run += v[i].w;
    }
}

// ---------------- invert CSR permutation: slot -> {edge, src, dst} ----------
__global__ __launch_bounds__(256) void invert(const int* __restrict__ eidx,
                                              const int* __restrict__ pos,
                                              const int* __restrict__ offsets,
                                              uint4* __restrict__ slotrec) {
    const int e = blockIdx.x * 256 + threadIdx.x;
    if (e < N_EDGES) {
        const int src = eidx[e];
        const int dst = eidx[N_EDGES + e];
        const int slot = offsets[dst] + pos[e];
        slotrec[slot] = uint4{(unsigned)e, (unsigned)src, (unsigned)dst, 0u};
    }
}

// ------- node precompute (pre = nf @ B128x128) + out init (out = nf) -------
__global__ __launch_bounds__(256) void node_pre_mfma(
    const float* __restrict__ nf, const short8* __restrict__ wfN,
    unsigned short* __restrict__ pre, float* __restrict__ out)
{
    __shared__ short ost[4][2048];   // per-wave 16x128 out stage
    const int tid = threadIdx.x;
    const int w = tid >> 6, lane = tid & 63;
    const int m16 = lane & 15, quad = lane >> 4;
    const int n0 = blockIdx.x * 64 + w * 16;

    // ---- out = nf (coalesced block copy; required for boundary atomics
    //      and degree-0 nodes in edge_mfma's reduction) ----
    {
        const int nbase = blockIdx.x * 64;
        const int nrem = min(64, N_NODES - nbase);
        const float4* s4 = (const float4*)(nf + (size_t)nbase * ND);
        float4* d4 = (float4*)(out + (size_t)nbase * ND);
        const int tot = nrem * (ND / 4);
        for (int i = tid; i < tot; i += 256) d4[i] = s4[i];
    }

    short8 a[4];
    #pragma unroll
    for (int kt = 0; kt < 4; ++kt) {
        const int node = min(n0 + m16, N_NODES - 1);
        const float* pn = nf + (size_t)node * ND + kt * 32 + quad * 8;
        const float4 f0 = *(const float4*)pn;
        const float4 f1 = *(const float4*)(pn + 4);
        a[kt] = pack8(pkbf(f0.x, f0.y), pkbf(f0.z, f0.w),
                      pkbf(f1.x, f1.y), pkbf(f1.z, f1.w));
    }
    f32x4 acc[8];
    #pragma unroll
    for (int nt = 0; nt < 8; ++nt) acc[nt] = f32x4{0.f, 0.f, 0.f, 0.f};
    #pragma unroll
    for (int kt = 0; kt < 4; ++kt) {
        #pragma unroll
        for (int nt = 0; nt < 8; ++nt)
            acc[nt] = MFMA16(a[kt], wfN[(size_t)(kt * 8 + nt) * 64 + lane], acc[nt]);
    }
    short* o = &ost[w][0];
    #pragma unroll
    for (int nt = 0; nt < 8; ++nt)
        #pragma unroll
        for (int r = 0; r < 4; ++r)
            o[(quad * 4 + r) * 128 + nt * 16 + m16] = f2bf(acc[nt][r]);  // no relu
    asm volatile("s_waitcnt lgkmcnt(0)" ::: "memory");
    #pragma unroll
    for (int i = 0; i < 4; ++i) {
        const int row = i * 4 + quad;
        const int node = n0 + row;
        if (node < N_NODES) {
            const uint4 v = ((const uint4*)(o + row * 128))[m16];
            *((uint4*)(pre + (size_t)node * 128) + m16) = v;
        }
    }
}

// ------ fused 4-layer edge MLP over CSR SLOTS + in-block segment-sum --------
// R3-verified compute core (coalesced gather via LDS transpose, 2 tiles/wave,
// swapped-operand MFMA chains). Processing in CSR-slot order makes dst
// monotone within the block, so after L4 the block segment-sums its 128
// staged slot-outputs in LDS and writes FINISHED out rows (nf + sum) with
// coalesced stores. Only the <=2 nodes straddling a block boundary use
// atomicAdd of the partial sum (out pre-initialized to nf). This deletes
// the 307MB msgs HBM round-trip and the gather2 kernel entirely.
__global__ __launch_bounds__(256, 4) void edge_mfma(
    const float* __restrict__ ef, const uint4* __restrict__ slotrec,
    const unsigned short* __restrict__ pre,
    const int* __restrict__ offsets, const short8* __restrict__ wfE,
    const float* __restrict__ be1, const float* __restrict__ be2,
    const float* __restrict__ bn1, const float* __restrict__ bn2,
    const float* __restrict__ nf, float* __restrict__ out)
{
    constexpr int TE = 128;
    __shared__ __align__(16) char sws[4][9216];
    __shared__ int dstlds[TE];

    const int tid = threadIdx.x;
    const int s0 = blockIdx.x * TE;
    const bool hasB = (s0 + 64) < N_EDGES;          // block-uniform (last block: 64 slots)
    const int w = tid >> 6, lane = tid & 63;
    const int m16 = lane & 15, q = lane >> 4;
    const int er0 = w * 16;
    char* swsb = &sws[w][0];

    // ---- front-load ef loads (slot -> edge indirection; 256B rows) ----
    float4 efv[2][4];
    {
        const uint4 rA = slotrec[s0 + er0 + m16];
        const float* pe = ef + (size_t)rA.x * ED + q * 8;
        efv[0][0] = *(const float4*)pe;
        efv[0][1] = *(const float4*)(pe + 4);
        efv[0][2] = *(const float4*)(pe + 32);
        efv[0][3] = *(const float4*)(pe + 36);
        if (hasB) {
            const uint4 rB = slotrec[s0 + 64 + er0 + m16];
            const float* pe2 = ef + (size_t)rB.x * ED + q * 8;
            efv[1][0] = *(const float4*)pe2;
            efv[1][1] = *(const float4*)(pe2 + 4);
            efv[1][2] = *(const float4*)(pe2 + 32);
            efv[1][3] = *(const float4*)(pe2 + 36);
        }
    }

    // ---- gather: 4 lanes/slot, both tiles' loads issued before LDS writes ----
    {
        const int et = tid >> 2, p4 = tid & 3;      // et in [16w,16w+16)
        const uint4 rA = slotrec[s0 + et];
        const int srcA = (int)rA.y;
        const int dstA = (int)rA.z;
        const uint4* paA = (const uint4*)(pre + (size_t)srcA * 128);
        const uint4* pdA = (const uint4*)(pre + (size_t)dstA * 128);
        const uint4 uaA = paA[p4];
        const uint4 udA = pdA[4 + p4];
        const uint4 s0A = pdA[8 + 2 * p4];
        const uint4 s1A = pdA[9 + 2 * p4];

        uint4 uaB, udB, s0B, s1B;
        int dstB = 0;
        if (hasB) {
            const uint4 rB = slotrec[s0 + 64 + et];
            const int srcB = (int)rB.y;
            dstB = (int)rB.z;
            const uint4* paB = (const uint4*)(pre + (size_t)srcB * 128);
            const uint4* pdB = (const uint4*)(pre + (size_t)dstB * 128);
            uaB = paB[p4];
            udB = pdB[4 + p4];
            s0B = pdB[8 + 2 * p4];
            s1B = pdB[9 + 2 * p4];
        }
        const float4 b0 = ((const float4*)be1)[2 * p4];
        const float4 b1 = ((const float4*)be1)[2 * p4 + 1];

        char* wbase = &sws[et >> 4][0] + (et & 15) * 144;
        {
            float4 r0, r1;
            r0.x = bflo(uaA.x) + bflo(udA.x) + b0.x;
            r0.y = bfhi(uaA.x) + bfhi(udA.x) + b0.y;
            r0.z = bflo(uaA.y) + bflo(udA.y) + b0.z;
            r0.w = bfhi(uaA.y) + bfhi(udA.y) + b0.w;
            r1.x = bflo(uaA.z) + bflo(udA.z) + b1.x;
            r1.y = bfhi(uaA.z) + bfhi(udA.z) + b1.y;
            r1.z = bflo(uaA.w) + bflo(udA.w) + b1.z;
            r1.w = bfhi(uaA.w) + bfhi(udA.w) + b1.w;
            *(float4*)(wbase + p4 * 32) = r0;
            *(float4*)(wbase + p4 * 32 + 16) = r1;
            *(uint4*)(wbase + 2304 + p4 * 32) = s0A;
            *(uint4*)(wbase + 2304 + p4 * 32 + 16) = s1A;
            if (p4 == 3) dstlds[et] = dstA;
        }
        if (hasB) {
            float4 r0, r1;
            r0.x = bflo(uaB.x) + bflo(udB.x) + b0.x;
            r0.y = bfhi(uaB.x) + bfhi(udB.x) + b0.y;
            r0.z = bflo(uaB.y) + bflo(udB.y) + b0.z;
            r0.w = bfhi(uaB.y) + bfhi(udB.y) + b0.w;
            r1.x = bflo(uaB.z) + bflo(udB.z) + b1.x;
            r1.y = bfhi(uaB.z) + bfhi(udB.z) + b1.y;
            r1.z = bflo(uaB.w) + bflo(udB.w) + b1.z;
            r1.w = bfhi(uaB.w) + bfhi(udB.w) + b1.w;
            *(float4*)(wbase + 4608 + p4 * 32) = r0;
            *(float4*)(wbase + 4608 + p4 * 32 + 16) = r1;
            *(uint4*)(wbase + 4608 + 2304 + p4 * 32) = s0B;
            *(uint4*)(wbase + 4608 + 2304 + p4 * 32 + 16) = s1B;
            if (p4 == 3) dstlds[64 + et] = dstB;
        }
    }
    // wave-local LDS handoff (all writes by this wave's lanes)
    asm volatile("s_waitcnt lgkmcnt(0)" ::: "memory");

    short8 aef[2][2];
    #pragma unroll
    for (int t = 0; t < 2; ++t) {
        aef[t][0] = pack8(pkbf(efv[t][0].x, efv[t][0].y), pkbf(efv[t][0].z, efv[t][0].w),
                          pkbf(efv[t][1].x, efv[t][1].y), pkbf(efv[t][1].z, efv[t][1].w));
        aef[t][1] = pack8(pkbf(efv[t][2].x, efv[t][2].y), pkbf(efv[t][2].z, efv[t][2].w),
                          pkbf(efv[t][3].x, efv[t][3].y), pkbf(efv[t][3].z, efv[t][3].w));
    }

    // ---- L1: C[h1][slot] = l1init + We1e^T x ef (both tiles share frags) ----
    f32x4 acc1[2][2];
    #pragma unroll
    for (int t = 0; t < 2; ++t)
        #pragma unroll
        for (int mt = 0; mt < 2; ++mt)
            acc1[t][mt] = *(const f32x4*)(swsb + t * 4608 + m16 * 144 + mt * 64 + q * 16);
    #pragma unroll
    for (int kt = 0; kt < 2; ++kt)
        #pragma unroll
        for (int mt = 0; mt < 2; ++mt) {
            const short8 wf = wfE[(size_t)(kt * 2 + mt) * 64 + lane];
            acc1[0][mt] = MFMA16(wf, aef[0][kt], acc1[0][mt]);
            acc1[1][mt] = MFMA16(wf, aef[1][kt], acc1[1][mt]);
        }

    short8 b2[2];
    #pragma unroll
    for (int t = 0; t < 2; ++t)
        b2[t] = pack8(prelu(acc1[t][0][0], acc1[t][0][1]), prelu(acc1[t][0][2], acc1[t][0][3]),
                      prelu(acc1[t][1][0], acc1[t][1][1]), prelu(acc1[t][1][2], acc1[t][1][3]));

    // ---- L2: msg(128) = relu(We2^T x h + be2) ----
    f32x4 acc2[2][8];
    #pragma unroll
    for (int mt = 0; mt < 8; ++mt) {
        const float4 bb = *(const float4*)(be2 + mt * 16 + q * 4);
        const short8 wf = wfE[(size_t)(4 + mt) * 64 + lane];
        acc2[0][mt] = f32x4{bb.x, bb.y, bb.z, bb.w};
        acc2[1][mt] = acc2[0][mt];
        acc2[0][mt] = MFMA16(wf, b2[0], acc2[0][mt]);
        acc2[1][mt] = MFMA16(wf, b2[1], acc2[1][mt]);
    }
    short8 b3[2][4];
    #pragma unroll
    for (int t = 0; t < 2; ++t)
        #pragma unroll
        for (int kt = 0; kt < 4; ++kt)
            b3[t][kt] = pack8(prelu(acc2[t][2 * kt][0], acc2[t][2 * kt][1]),
                              prelu(acc2[t][2 * kt][2], acc2[t][2 * kt][3]),
                              prelu(acc2[t][2 * kt + 1][0], acc2[t][2 * kt + 1][1]),
                              prelu(acc2[t][2 * kt + 1][2], acc2[t][2 * kt + 1][3]));

    // ---- L3: h2(64) = relu(a3 + bn1 + Wn1b^T x msg) ----
    f32x4 acc3[2][4];
    #pragma unroll
    for (int mt = 0; mt < 4; ++mt) {
        const float4 bb = *(const float4*)(bn1 + mt * 16 + q * 4);
        #pragma unroll
        for (int t = 0; t < 2; ++t) {
            const uint2 ua = *(const uint2*)(swsb + t * 4608 + 2304 + m16 * 144 + mt * 32 + q * 8);
            acc3[t][mt] = f32x4{bb.x + bflo(ua.x), bb.y + bfhi(ua.x),
                                bb.z + bflo(ua.y), bb.w + bfhi(ua.y)};
        }
    }
    #pragma unroll
    for (int kt = 0; kt < 4; ++kt)
        #pragma unroll
        for (int mt = 0; mt < 4; ++mt) {
            const short8 wf = wfE[(size_t)(12 + kt * 4 + mt) * 64 + lane];
            acc3[0][mt] = MFMA16(wf, b3[0][kt], acc3[0][mt]);
            acc3[1][mt] = MFMA16(wf, b3[1][kt], acc3[1][mt]);
        }
    short8 b4[2][2];
    #pragma unroll
    for (int t = 0; t < 2; ++t)
        #pragma unroll
        for (int kt = 0; kt < 2; ++kt)
            b4[t][kt] = pack8(prelu(acc3[t][2 * kt][0], acc3[t][2 * kt][1]),
                              prelu(acc3[t][2 * kt][2], acc3[t][2 * kt][3]),
                              prelu(acc3[t][2 * kt + 1][0], acc3[t][2 * kt + 1][1]),
                              prelu(acc3[t][2 * kt + 1][2], acc3[t][2 * kt + 1][3]));

    // ---- L4: out(128) = relu(Wn2^T x h2 + bn2) ----
    f32x4 acc4[2][8];
    #pragma unroll
    for (int mt = 0; mt < 8; ++mt) {
        const float4 bb = *(const float4*)(bn2 + mt * 16 + q * 4);
        acc4[0][mt] = f32x4{bb.x, bb.y, bb.z, bb.w};
        acc4[1][mt] = acc4[0][mt];
    }
    #pragma unroll
    for (int kt = 0; kt < 2; ++kt)
        #pragma unroll
        for (int mt = 0; mt < 8; ++mt) {
            const short8 wf = wfE[(size_t)(28 + kt * 8 + mt) * 64 + lane];
            acc4[0][mt] = MFMA16(wf, b4[0][kt], acc4[0][mt]);
            acc4[1][mt] = MFMA16(wf, b4[1][kt], acc4[1][mt]);
        }

    // ---- stage bf16 slot-outputs to LDS (aliases dead gather staging) ----
    // per wave region: tile t at t*4608, row (slot m16) stride 272B; layout
    // is channel-linear (byte = channel*2) per row.
    #pragma unroll
    for (int t = 0; t < 2; ++t)
        #pragma unroll
        for (int mt = 0; mt < 8; ++mt) {
            uint2 wv;
            wv.x = prelu(acc4[t][mt][0], acc4[t][mt][1]);
            wv.y = prelu(acc4[t][mt][2], acc4[t][mt][3]);
            *(uint2*)(swsb + t * 4608 + m16 * 272 + mt * 32 + q * 8) = wv;
        }
    __syncthreads();   // all waves' stages + dstlds visible block-wide

    // ---- segment-sum by dst (monotone over slots) -> finished out rows ----
    const int nsl = hasB ? 128 : 64;
    const int send = s0 + nsl;
    const int dstlo = dstlds[0];
    const int dsthi = dstlds[nsl - 1];
    const int g = tid >> 4, j = tid & 15;    // 16 groups x 16 lanes; lane j owns cols j*8..j*8+7
    for (int n = dstlo + g; n <= dsthi; n += 16) {
        const int beg = offsets[n];
        const int end = offsets[n + 1];
        const int lo = max(beg, s0);
        const int hi = min(end, send);
        if (lo >= hi) continue;              // empty node in span: out stays nf
        float s[8] = {0.f, 0.f, 0.f, 0.f, 0.f, 0.f, 0.f, 0.f};
        for (int sl = lo - s0; sl < hi - s0; ++sl) {
            const int ww = (sl >> 4) & 3;    // wave that staged this slot
            const int tt = sl >> 6;          // tile
            const int mm = sl & 15;          // row within tile
            const uint4 u = *(const uint4*)(&sws[ww][0] + tt * 4608 + mm * 272 + j * 16);
            s[0] += bflo(u.x); s[1] += bfhi(u.x);
            s[2] += bflo(u.y); s[3] += bfhi(u.y);
            s[4] += bflo(u.z); s[5] += bfhi(u.z);
            s[6] += bflo(u.w); s[7] += bfhi(u.w);
        }
        if (beg >= s0 && end <= send) {
            // node fully owned by this block: out = nf + sum (coalesced store)
            const float4* pn = (const float4*)(nf + (size_t)n * ND) + j * 2;
            const float4 n0 = pn[0];
            const float4 n1 = pn[1];
            float4 o0{s[0] + n0.x, s[1] + n0.y, s[2] + n0.z, s[3] + n0.w};
            float4 o1{s[4] + n1.x, s[5] + n1.y, s[6] + n1.z, s[7] + n1.w};
            float4* po = (float4*)(out + (size_t)n * ND) + j * 2;
            po[0] = o0;
            po[1] = o1;
        } else {
            // boundary node: add partial onto nf-pre-initialized out
            float* po = out + (size_t)n * ND + j * 8;
            #pragma unroll
            for (int r = 0; r < 8; ++r) atomicAdd(po + r, s[r]);
        }
    }
}

extern "C" void kernel_launch(void* const* d_in, const int* in_sizes, int n_in,
                              void* d_out, int out_size, void* d_ws, size_t ws_size,
                              hipStream_t stream) {
    const float* nf  = (const float*)d_in[0];
    const float* ef  = (const float*)d_in[1];
    const int*  eidx = (const int*)d_in[2];
    const float* We1 = (const float*)d_in[3];
    const float* be1 = (const float*)d_in[4];
    const float* We2 = (const float*)d_in[5];
    const float* be2 = (const float*)d_in[6];
    const float* Wn1 = (const float*)d_in[7];
    const float* bn1 = (const float*)d_in[8];
    const float* Wn2 = (const float*)d_in[9];
    const float* bn2 = (const float*)d_in[10];
    float* out = (float*)d_out;

    char* ws = (char*)d_ws;
    uint4* slotrec       = (uint4*)(ws + WS_SLOTREC);
    unsigned short* pre  = (unsigned short*)(ws + WS_PRE);
    int* pos             = (int*)(ws + WS_POS);
    int* counts          = (int*)(ws + WS_COUNTS);
    int* offsets         = (int*)(ws + WS_OFFSETS);
    short8* wfE          = (short8*)(ws + WS_WFE);
    short8* wfN          = (short8*)(ws + WS_WFN);
    (void)ws_size; (void)WS_END;

    hipMemsetAsync(counts, 0, (size_t)COUNTS_PAD * 4, stream);
    wprep<<<19, 256, 0, stream>>>(We1, We2, Wn1, Wn2, wfE, wfN);
    hist_pos<<<(N_EDGES + 255) / 256, 256, 0, stream>>>(eidx, counts, pos);
    scan_kernel<<<1, 1024, 0, stream>>>(counts, offsets);
    invert<<<(N_EDGES + 255) / 256, 256, 0, stream>>>(eidx, pos, offsets, slotrec);
    node_pre_mfma<<<(N_NODES + 63) / 64, 256, 0, stream>>>(nf, wfN, pre, out);
    edge_mfma<<<(N_EDGES + 127) / 128, 256, 0, stream>>>(
        ef, slotrec, pre, offsets, wfE, be1, be2, bn1, bn2, nf, out);
}